// Round 1
// 1114.835 us; speedup vs baseline: 1.5303x; 1.5303x over previous
//
#include <hip/hip_runtime.h>
#include <hip/hip_bf16.h>
#include <cstdint>
#include <cstddef>

// Problem constants (PropSTGformer)
#define B_   4
#define T_   24
#define NN_  2048
#define D_   256
#define H_   8
#define HD_  32
#define BT_  (B_*T_)           // 96
#define MTOK (B_*T_*NN_)       // 196608 tokens

using bf16 = __hip_bfloat16;

typedef __attribute__((ext_vector_type(8))) short bf16x8;   // MFMA A/B frag (4 VGPRs)
typedef __attribute__((ext_vector_type(4))) float f32x4;    // MFMA C/D frag

__device__ __forceinline__ float bf2f(bf16 v) { return __bfloat162float(v); }

// async global->LDS, 16B per lane. LDS dest must be wave-uniform base (+lane*16 implicit).
__device__ __forceinline__ void async_copy16(const void* g, void* l) {
  __builtin_amdgcn_global_load_lds(
      (const __attribute__((address_space(1))) void*)g,
      (__attribute__((address_space(3))) void*)l,
      16, 0, 0);
}

// sum over the 32-lane half-wave group (all lanes get result)
__device__ __forceinline__ float red32(float v) {
  v += __shfl_xor(v, 1, 64);
  v += __shfl_xor(v, 2, 64);
  v += __shfl_xor(v, 4, 64);
  v += __shfl_xor(v, 8, 64);
  v += __shfl_xor(v, 16, 64);
  return v;
}

// ---------------------------------------------------------------- convert f32 -> bf16
__global__ void k_convert(const float* __restrict__ in, bf16* __restrict__ out, int n4) {
  int i = blockIdx.x * blockDim.x + threadIdx.x;
  if (i < n4) {
    float4 v = ((const float4*)in)[i];
    bf16 t[4] = {__float2bfloat16(v.x), __float2bfloat16(v.y),
                 __float2bfloat16(v.z), __float2bfloat16(v.w)};
    ((ushort4*)out)[i] = *(ushort4*)t;
  }
}

// ---------------------------------------------------------------- bf16 GEMM, C = A * Bw^T
// A: [M x KD] row-major bf16. Bw: [ncols x KD] row-major bf16 (i.e. B[k][n] = Bw[n][k]).
// 128x128 tile, BK=64, 4 waves each computing 64x64 (4x4 tiles of 16x16x32 MFMA).
template<int KD, bool OUTF32>
__global__ __launch_bounds__(256, 2)
void k_gemm(const bf16* __restrict__ A, const bf16* __restrict__ Bw,
            void* __restrict__ Cout, const float* __restrict__ bias, int ncols) {
  __shared__ bf16 As[128 * 64];
  __shared__ bf16 Bs[128 * 64];
  const int tid  = threadIdx.x;
  const int wave = tid >> 6, lane = tid & 63;
  const int quad = lane >> 4, l16 = lane & 15;
  const long row0 = (long)blockIdx.x * 128;
  const long col0 = (long)blockIdx.y * 128;
  const int wm = (wave & 1) * 64, wn = (wave >> 1) * 64;
  const int srow = lane >> 3;          // row within 8-row staging chunk
  const int skb  = (lane & 7) * 8;     // k-element offset (8 bf16 = 16B)

  f32x4 acc[4][4];
  const f32x4 z = {0.f, 0.f, 0.f, 0.f};
#pragma unroll
  for (int a = 0; a < 4; ++a)
#pragma unroll
    for (int b = 0; b < 4; ++b) acc[a][b] = z;

  for (int k0 = 0; k0 < KD; k0 += 64) {
#pragma unroll
    for (int i = 0; i < 4; ++i) {
      const int c = wave * 4 + i;          // chunk id, wave-uniform
      const int r = c * 8 + srow;          // tile row
      async_copy16(A  + (row0 + r) * KD + k0 + skb, (char*)As + c * 1024);
      async_copy16(Bw + (col0 + r) * KD + k0 + skb, (char*)Bs + c * 1024);
    }
    __syncthreads();
#pragma unroll
    for (int kk = 0; kk < 64; kk += 32) {
      bf16x8 af[4], bfr[4];
#pragma unroll
      for (int i = 0; i < 4; ++i)
        af[i] = *(const bf16x8*)(As + (wm + i * 16 + l16) * 64 + kk + quad * 8);
#pragma unroll
      for (int i = 0; i < 4; ++i)
        bfr[i] = *(const bf16x8*)(Bs + (wn + i * 16 + l16) * 64 + kk + quad * 8);
#pragma unroll
      for (int mi = 0; mi < 4; ++mi)
#pragma unroll
        for (int ni = 0; ni < 4; ++ni)
          acc[mi][ni] = __builtin_amdgcn_mfma_f32_16x16x32_bf16(af[mi], bfr[ni], acc[mi][ni], 0, 0, 0);
    }
    __syncthreads();
  }

  // epilogue: C/D layout col=lane&15, row=quad*4+reg
#pragma unroll
  for (int mi = 0; mi < 4; ++mi)
#pragma unroll
    for (int ni = 0; ni < 4; ++ni) {
      const long colg = col0 + wn + ni * 16 + l16;
#pragma unroll
      for (int r = 0; r < 4; ++r) {
        const long rowg = row0 + wm + mi * 16 + quad * 4 + r;
        const float v = acc[mi][ni][r];
        if (OUTF32) {
          ((float*)Cout)[rowg * ncols + colg] = v + bias[colg];
        } else {
          ((bf16*)Cout)[rowg * ncols + colg] = __float2bfloat16(v);
        }
      }
    }
}

// ---------------------------------------------------------------- spatial stats
// per (bt, h): kvs[m][d] = sum_n khat[n][m]*v[n][d]  (32x32), ks_sum[m] = sum_n khat[n][m]
// stats layout: [bt][h][1056] = 1024 kvs + 32 ks_sum, fp32
// 256 threads = 4 waves; wave w covers tokens {w*64 + 256*j + lane}.
__global__ __launch_bounds__(256)
void k_spatial_stats(const bf16* __restrict__ qkv, float* __restrict__ stats) {
  const int bt = blockIdx.x, h = blockIdx.y;
  const int tid = threadIdx.x;
  const int wave = tid >> 6, lane = tid & 63;
  __shared__ float lk[256][36];   // khat, token-major, +pad
  __shared__ float lv[256][36];   // v
  const int mg = lane >> 3, dg = lane & 7;
  const int m0 = mg * 4, d0 = dg * 4;
  float acc[4][4] = {};
  float ssum[4] = {0.f, 0.f, 0.f, 0.f};

  for (int c = wave * 64; c < NN_; c += 256) {
    const size_t row = ((size_t)bt * NN_ + c + lane) * 768;
    bf16 kb[32], vb[32];
    const uint4* kp = (const uint4*)(qkv + row + 256 + h * 32);
    const uint4* vp = (const uint4*)(qkv + row + 512 + h * 32);
#pragma unroll
    for (int j = 0; j < 4; ++j) { ((uint4*)kb)[j] = kp[j]; ((uint4*)vb)[j] = vp[j]; }
    float kf[32]; float ss = 0.f;
#pragma unroll
    for (int j = 0; j < 32; ++j) { kf[j] = bf2f(kb[j]); ss += kf[j] * kf[j]; }
    const float sc = 1.f / fmaxf(sqrtf(ss), 1e-12f);
#pragma unroll
    for (int j = 0; j < 32; ++j) kf[j] *= sc;
    float vf[32];
#pragma unroll
    for (int j = 0; j < 32; ++j) vf[j] = bf2f(vb[j]);
    const int lrow = wave * 64 + lane;
#pragma unroll
    for (int j = 0; j < 8; ++j) {
      ((float4*)lk[lrow])[j] = ((float4*)kf)[j];
      ((float4*)lv[lrow])[j] = ((float4*)vf)[j];
    }
    __syncthreads();
#pragma unroll 2
    for (int t = 0; t < 64; ++t) {
      const int tr = wave * 64 + t;
      const float4 ka = *(const float4*)&lk[tr][m0];   // broadcast within wave (free)
      const float4 va = *(const float4*)&lv[tr][d0];
      const float km[4] = {ka.x, ka.y, ka.z, ka.w};
      const float vm[4] = {va.x, va.y, va.z, va.w};
#pragma unroll
      for (int i = 0; i < 4; ++i) {
        ssum[i] += km[i];
#pragma unroll
        for (int j = 0; j < 4; ++j) acc[i][j] += km[i] * vm[j];
      }
    }
    __syncthreads();
  }

  // cross-wave reduction via LDS (reuse lk storage: 4 x 1056 floats)
  float* rbuf = (float*)lk;
  float* wb = rbuf + wave * 1056;
#pragma unroll
  for (int i = 0; i < 4; ++i) {
    float4 o = {acc[i][0], acc[i][1], acc[i][2], acc[i][3]};
    *(float4*)&wb[(m0 + i) * 32 + d0] = o;
  }
  if (dg == 0) {
#pragma unroll
    for (int i = 0; i < 4; ++i) wb[1024 + m0 + i] = ssum[i];
  }
  __syncthreads();
  float* base = stats + ((size_t)bt * H_ + h) * 1056;
  for (int e = tid; e < 1056; e += 256)
    base[e] = rbuf[e] + rbuf[1056 + e] + rbuf[2112 + e] + rbuf[3168 + e];
}

// ---------------------------------------------------------------- spatial output (v2)
// block = (32-token chunk c, bt); thread = (h, d). kvs column [m][d] in registers.
// qhat rows staged in LDS; 32-wide broadcast via 8x ds_read_b128 (uniform addr per
// d-group -> HW broadcast) instead of 32x ds_bpermute per token.
#define TCH 32
__global__ __launch_bounds__(256, 3)
void k_spatial_out(const bf16* __restrict__ qkv, const float* __restrict__ stats,
                   bf16* __restrict__ concat) {
  const int c  = blockIdx.x;
  const int bt = blockIdx.y;
  const int tid = threadIdx.x;
  const int h = tid >> 5, d = tid & 31;
  __shared__ float qhat[TCH][H_][HD_];   // 32 KB

  const float* sbase = stats + ((size_t)bt * H_ + h) * 1056;
  float kvcol[32];
#pragma unroll
  for (int m = 0; m < 32; ++m) kvcol[m] = sbase[m * 32 + d];
  const float kssd = sbase[1024 + d];

  const size_t tok0 = (size_t)bt * NN_ + (size_t)c * TCH;

  // phase 1: per-token L2 norm of q (one red32 each), store qhat rows to LDS
  for (int i = 0; i < TCH; i += 8) {
    float qf[8];
#pragma unroll
    for (int j = 0; j < 8; ++j)
      qf[j] = bf2f(qkv[(tok0 + i + j) * 768 + h * 32 + d]);
#pragma unroll
    for (int j = 0; j < 8; ++j) {
      const float qss = red32(qf[j] * qf[j]);
      qhat[i + j][h][d] = qf[j] * (1.f / fmaxf(sqrtf(qss), 1e-12f));
    }
  }
  __syncthreads();

  // phase 2: num = qhat_row . kvcol (broadcast LDS reads), den via red32
  for (int i = 0; i < TCH; i += 8) {
    float vf8[8];
#pragma unroll
    for (int j = 0; j < 8; ++j)
      vf8[j] = bf2f(qkv[(tok0 + i + j) * 768 + 512 + h * 32 + d]);
#pragma unroll
    for (int j = 0; j < 8; ++j) {
      float qr[32];
#pragma unroll
      for (int jj = 0; jj < 8; ++jj)
        ((float4*)qr)[jj] = ((const float4*)&qhat[i + j][h][0])[jj];
      float n0 = 0.f, n1 = 0.f, n2 = 0.f, n3 = 0.f;
#pragma unroll
      for (int m = 0; m < 32; m += 4) {
        n0 = fmaf(qr[m],     kvcol[m],     n0);
        n1 = fmaf(qr[m + 1], kvcol[m + 1], n1);
        n2 = fmaf(qr[m + 2], kvcol[m + 2], n2);
        n3 = fmaf(qr[m + 3], kvcol[m + 3], n3);
      }
      const float num = (n0 + n1) + (n2 + n3) + 2048.f * vf8[j];
      const float qo  = qhat[i + j][h][d];
      const float den = fmaxf(red32(qo * kssd) + 2048.f, 1e-5f);
      concat[(tok0 + i + j) * 512 + h * 32 + d] = __float2bfloat16(num / den);
    }
  }
}

// ---------------------------------------------------------------- temporal attention + output (v2)
// block = (n, b); thread = (h, d). khat/qhat rows staged in LDS f32 [t][h][32];
// the 32-wide broadcasts use 8x ds_read_b128 (uniform addr -> HW broadcast) instead
// of 32x ds_bpermute per token. One barrier total.
__global__ __launch_bounds__(256, 3)
void k_temporal_out(const bf16* __restrict__ qkv, bf16* __restrict__ concat) {
  const int n = blockIdx.x, b = blockIdx.y;
  const int tid = threadIdx.x;
  const int h = tid >> 5, d = tid & 31;
  __shared__ float khat[T_][H_][HD_];   // 24 KB
  __shared__ float qhat[T_][H_][HD_];   // 24 KB

  const size_t base = ((size_t)b * T_ * NN_ + n) * 768 + h * 32 + d;
  const size_t tstep = (size_t)NN_ * 768;

  // batched independent loads (MLP): v and k first
  float vf[T_], kfa[T_];
#pragma unroll
  for (int t = 0; t < T_; ++t) {
    kfa[t] = bf2f(qkv[base + t * tstep + 256]);
    vf[t]  = bf2f(qkv[base + t * tstep + 512]);
  }

  // phase 1a: normalize k rows, store khat; own-lane kss accumulates in-register
  float kssd = 0.f;
#pragma unroll
  for (int t = 0; t < T_; ++t) {
    const float ss = red32(kfa[t] * kfa[t]);
    const float kh = kfa[t] * (1.f / fmaxf(sqrtf(ss), 1e-12f));
    kssd += kh;
    khat[t][h][d] = kh;
  }

  // phase 1b: normalize q rows, store qhat (reuses kfa registers)
  float qfa[T_];
#pragma unroll
  for (int t = 0; t < T_; ++t) qfa[t] = bf2f(qkv[base + t * tstep]);
#pragma unroll
  for (int t = 0; t < T_; ++t) {
    const float ss = red32(qfa[t] * qfa[t]);
    qhat[t][h][d] = qfa[t] * (1.f / fmaxf(sqrtf(ss), 1e-12f));
  }
  __syncthreads();

  // phase 2: kvcol[m] = sum_t khat[t][m] * v[t][d]  (broadcast reads of khat rows)
  float kvcol[32];
#pragma unroll
  for (int m = 0; m < 32; ++m) kvcol[m] = 0.f;
#pragma unroll 2
  for (int t = 0; t < T_; ++t) {
    float kr[32];
#pragma unroll
    for (int j = 0; j < 8; ++j)
      ((float4*)kr)[j] = ((const float4*)&khat[t][h][0])[j];
    const float v = vf[t];
#pragma unroll
    for (int m = 0; m < 32; ++m) kvcol[m] = fmaf(kr[m], v, kvcol[m]);
  }

  // phase 3: outputs (no barrier needed: reads qhat from phase 1 + own kvcol)
#pragma unroll 2
  for (int t = 0; t < T_; ++t) {
    float qr[32];
#pragma unroll
    for (int j = 0; j < 8; ++j)
      ((float4*)qr)[j] = ((const float4*)&qhat[t][h][0])[j];
    float n0 = 0.f, n1 = 0.f, n2 = 0.f, n3 = 0.f;
#pragma unroll
    for (int m = 0; m < 32; m += 4) {
      n0 = fmaf(qr[m],     kvcol[m],     n0);
      n1 = fmaf(qr[m + 1], kvcol[m + 1], n1);
      n2 = fmaf(qr[m + 2], kvcol[m + 2], n2);
      n3 = fmaf(qr[m + 3], kvcol[m + 3], n3);
    }
    const float num = (n0 + n1) + (n2 + n3) + 24.f * vf[t];
    const float qo  = qhat[t][h][d];
    const float den = fmaxf(red32(qo * kssd) + 24.f, 1e-5f);
    const size_t tok = (size_t)(b * T_ + t) * NN_ + n;
    concat[tok * 512 + 256 + h * 32 + d] = __float2bfloat16(num / den);
  }
}

// ---------------------------------------------------------------- launch
extern "C" void kernel_launch(void* const* d_in, const int* in_sizes, int n_in,
                              void* d_out, int out_size, void* d_ws, size_t ws_size,
                              hipStream_t stream) {
  (void)in_sizes; (void)n_in; (void)out_size; (void)ws_size;
  const float* x     = (const float*)d_in[0];
  const float* w_qkv = (const float*)d_in[1];
  const float* w_out = (const float*)d_in[2];
  const float* b_out = (const float*)d_in[3];
  float* out = (float*)d_out;
  char* ws = (char*)d_ws;

  // workspace layout (bytes); concat aliases x_bf16 (dead after K1)
  bf16* concat = (bf16*)(ws);                       // 201,326,592 B (196608*512*2)
  bf16* xb     = (bf16*)(ws);                       // 100,663,296 B (aliased)
  bf16* qkv    = (bf16*)(ws + 201326592);           // 301,989,888 B
  float* stats = (float*)(ws + 503316480);          //   3,244,032 B
  bf16* wqkvb  = (bf16*)(ws + 506560512);           //     393,216 B
  bf16* woutb  = (bf16*)(ws + 506953728);           //     262,144 B
  // total: 507,215,872 B

  // converts
  k_convert<<<(MTOK * D_ / 4 + 255) / 256, 256, 0, stream>>>(x, xb, MTOK * D_ / 4);
  k_convert<<<(768 * 256 / 4 + 255) / 256, 256, 0, stream>>>(w_qkv, wqkvb, 768 * 256 / 4);
  k_convert<<<(256 * 512 / 4 + 255) / 256, 256, 0, stream>>>(w_out, woutb, 256 * 512 / 4);

  // qkv = x @ w_qkv^T   (M=196608, N=768, K=256)
  k_gemm<256, false><<<dim3(MTOK / 128, 768 / 128), 256, 0, stream>>>(xb, wqkvb, qkv, nullptr, 768);

  // spatial stats over N
  k_spatial_stats<<<dim3(BT_, H_), 256, 0, stream>>>(qkv, stats);

  // spatial + temporal outputs -> concat (bf16)
  k_spatial_out<<<dim3(NN_ / TCH, BT_), 256, 0, stream>>>(qkv, stats, concat);
  k_temporal_out<<<dim3(NN_, B_), 256, 0, stream>>>(qkv, concat);

  // final: out = concat @ w_out^T + b_out   (M=196608, N=256, K=512)
  k_gemm<512, true><<<dim3(MTOK / 128, 256 / 128), 256, 0, stream>>>(concat, woutb, out, b_out, 256);
}